// Round 1
// baseline (1011.594 us; speedup 1.0000x reference)
//
#include <hip/hip_runtime.h>

// Problem constants (from reference setup_inputs)
#define T_STEPS 120
#define BATCH   2048
#define HID     512
#define OUTN    2

// Output layout (flat, return order):
//  spk1_rec (T,B,H)  : 120*2048*512 = 125829120
//  mem1_rec (T,B,H)  : 125829120
//  spk2_rec (T,B,O)  : 491520
//  mem2_rec (T,B,O)  : 491520
//  hidden_spike_count: 1
//  output_spike_count: 1
#define SPK1_OFF 0LL
#define MEM1_OFF 125829120LL
#define SPK2_OFF 251658240LL
#define MEM2_OFF 252149760LL
#define CNT_OFF  252641280LL

__global__ void zero_counts_kernel(float* cnts) {
    cnts[0] = 0.0f;
    cnts[1] = 0.0f;
}

// One block per batch row b (512 threads = one per hidden neuron h).
// Hidden dynamics are independent per (b,h); output layer needs a per-t
// block reduction over H which we do with wave shuffles + LDS.
__global__ __launch_bounds__(512) void snn_fwd_kernel(
    const float* __restrict__ x,       // (B,T)
    const float* __restrict__ W1,      // (H,1)
    const float* __restrict__ W2,      // (O,H), already *H per setup
    const float* __restrict__ beta_h,  // (H)
    const float* __restrict__ thr_h,   // (H)
    const float* __restrict__ beta_o,  // (O)
    const float* __restrict__ thr_o,   // (O)
    float* __restrict__ spk1_rec,
    float* __restrict__ mem1_rec,
    float* __restrict__ spk2_rec,
    float* __restrict__ mem2_rec,
    float* __restrict__ cnts)
{
    const int h = threadIdx.x;
    const int b = blockIdx.x;
    const int wid  = h >> 6;
    const int lane = h & 63;

    __shared__ float xs[T_STEPS];
    __shared__ float red[8][2];
    __shared__ float redc[8];

    if (h < T_STEPS) xs[h] = x[b * T_STEPS + h];

    const float w1 = W1[h];
    const float bh = fminf(fmaxf(beta_h[h], 0.0f), 1.0f);
    const float th = thr_h[h];
    const float w20 = W2[h];          // W2[0][h]
    const float w21 = W2[HID + h];    // W2[1][h]

    float bo0 = 0.f, bo1 = 0.f, to0 = 0.f, to1 = 0.f;
    if (h == 0) {
        bo0 = fminf(fmaxf(beta_o[0], 0.0f), 1.0f);
        bo1 = fminf(fmaxf(beta_o[1], 0.0f), 1.0f);
        to0 = thr_o[0];
        to1 = thr_o[1];
    }

    float m1 = 0.0f;
    float m2_0 = 0.0f, m2_1 = 0.0f;
    int hc = 0;  // per-thread hidden spike count
    int oc = 0;  // output spike count (thread 0 only)

    __syncthreads();

    for (int t = 0; t < T_STEPS; ++t) {
        const float xt = xs[t];
        // mem1 = bh*mem1 + xt*w1  -- exact op order, no FMA contraction,
        // to match the numpy fp32 reference bit-for-bit.
        m1 = __fadd_rn(__fmul_rn(bh, m1), __fmul_rn(xt, w1));
        const bool fired = (m1 > th);
        const float spk = fired ? 1.0f : 0.0f;
        if (fired) { m1 = 0.0f; hc++; }

        const long long idx1 = (long long)t * (BATCH * HID) + (long long)b * HID + h;
        spk1_rec[idx1] = spk;
        mem1_rec[idx1] = m1;

        // cur2[o] = sum_h spk * W2[o][h] : wave shuffle reduce, then LDS.
        float c0 = spk * w20;
        float c1 = spk * w21;
        // Spikes are extremely rare; skip the shuffle chain when the whole
        // wave is silent (wave-uniform branch, no divergence).
        if (__ballot(fired) != 0ULL) {
            for (int off = 32; off > 0; off >>= 1) {
                c0 += __shfl_down(c0, off, 64);
                c1 += __shfl_down(c1, off, 64);
            }
        }
        if (lane == 0) { red[wid][0] = c0; red[wid][1] = c1; }
        __syncthreads();

        if (h == 0) {
            float cur0 = 0.0f, cur1 = 0.0f;
            #pragma unroll
            for (int w = 0; w < 8; ++w) { cur0 += red[w][0]; cur1 += red[w][1]; }
            m2_0 = __fadd_rn(__fmul_rn(bo0, m2_0), cur0);
            m2_1 = __fadd_rn(__fmul_rn(bo1, m2_1), cur1);
            const bool f0 = (m2_0 > to0);
            const bool f1 = (m2_1 > to1);
            const float s0 = f0 ? 1.0f : 0.0f;
            const float s1 = f1 ? 1.0f : 0.0f;
            if (f0) { m2_0 = 0.0f; oc++; }
            if (f1) { m2_1 = 0.0f; oc++; }
            const long long idx2 = (long long)t * (BATCH * OUTN) + (long long)b * OUTN;
            spk2_rec[idx2]     = s0;
            spk2_rec[idx2 + 1] = s1;
            mem2_rec[idx2]     = m2_0;
            mem2_rec[idx2 + 1] = m2_1;
        }
        __syncthreads();  // protect red[] before next timestep's writes
    }

    // Block-reduce hidden spike count, then device-scope atomics into d_out.
    float fc = (float)hc;
    for (int off = 32; off > 0; off >>= 1) fc += __shfl_down(fc, off, 64);
    if (lane == 0) redc[wid] = fc;
    __syncthreads();
    if (h == 0) {
        float tot = 0.0f;
        #pragma unroll
        for (int w = 0; w < 8; ++w) tot += redc[w];
        atomicAdd(&cnts[0], tot);
        atomicAdd(&cnts[1], (float)oc);
    }
}

extern "C" void kernel_launch(void* const* d_in, const int* in_sizes, int n_in,
                              void* d_out, int out_size, void* d_ws, size_t ws_size,
                              hipStream_t stream) {
    const float* x      = (const float*)d_in[0];
    const float* W1     = (const float*)d_in[1];
    const float* W2     = (const float*)d_in[2];
    const float* beta_h = (const float*)d_in[3];
    const float* thr_h  = (const float*)d_in[4];
    const float* beta_o = (const float*)d_in[5];
    const float* thr_o  = (const float*)d_in[6];

    float* out  = (float*)d_out;
    float* spk1 = out + SPK1_OFF;
    float* mem1 = out + MEM1_OFF;
    float* spk2 = out + SPK2_OFF;
    float* mem2 = out + MEM2_OFF;
    float* cnts = out + CNT_OFF;

    // d_out is poisoned 0xAA before timed launches; zero the atomic slots.
    zero_counts_kernel<<<1, 1, 0, stream>>>(cnts);

    snn_fwd_kernel<<<BATCH, HID, 0, stream>>>(
        x, W1, W2, beta_h, thr_h, beta_o, thr_o,
        spk1, mem1, spk2, mem2, cnts);
}